// Round 5
// baseline (1201.892 us; speedup 1.0000x reference)
//
#include <hip/hip_runtime.h>
#include <hip/hip_bf16.h>
#include <stdint.h>

#define N_NODES 20000
#define DIM     768
#define NREL    8
#define NEDGE   320000
#define NSEG    (N_NODES * NREL)   // 160000
#define GKA     6144   // NREL*DIM  (aggregated part of K)
#define GK      6912   // GKA + DIM (full K incl. root)
#define NPW     2      // nodes per wave in aggregate

typedef short short8 __attribute__((ext_vector_type(8)));
typedef float f32x4  __attribute__((ext_vector_type(4)));

__device__ __forceinline__ void async_load16(const void* g, void* l) {
  __builtin_amdgcn_global_load_lds((const __attribute__((address_space(1))) void*)g,
                                   (__attribute__((address_space(3))) void*)l,
                                   16, 0, 0);
}

__device__ __forceinline__ float bf_lo(uint32_t v) {
  return __builtin_bit_cast(float, v << 16);
}
__device__ __forceinline__ float bf_hi(uint32_t v) {
  return __builtin_bit_cast(float, v & 0xffff0000u);
}
__device__ __forceinline__ uint32_t pack_bf16x2(float a, float b) {
  uint32_t lo = __builtin_bit_cast(unsigned short, __float2bfloat16(a));
  uint32_t hi = __builtin_bit_cast(unsigned short, __float2bfloat16(b));
  return lo | (hi << 16);
}

// ---------------------------------------------------------------- segment CSR build
__global__ void seg_count_kernel(const int* __restrict__ dst, const int* __restrict__ et,
                                 int* __restrict__ segcnt, int e_cnt) {
  int e = blockIdx.x * 256 + threadIdx.x;
  if (e < e_cnt) atomicAdd(&segcnt[dst[e] * NREL + et[e]], 1);
}

__global__ void block_scan_kernel(const int* __restrict__ in, int* __restrict__ out,
                                  int* __restrict__ partials, int n) {
  __shared__ int wsum[16];
  const int t = threadIdx.x, lane = t & 63, wave = t >> 6;
  const int i = blockIdx.x * 1024 + t;
  int v = (i < n) ? in[i] : 0;
  int s = v;
#pragma unroll
  for (int off = 1; off < 64; off <<= 1) {
    int u = __shfl_up(s, off, 64);
    if (lane >= off) s += u;
  }
  if (lane == 63) wsum[wave] = s;
  __syncthreads();
  if (t < 16) {
    int w = wsum[t];
#pragma unroll
    for (int off = 1; off < 16; off <<= 1) {
      int u = __shfl_up(w, off, 64);
      if (t >= off) w += u;
    }
    wsum[t] = w;
  }
  __syncthreads();
  const int basew = (wave > 0) ? wsum[wave - 1] : 0;
  if (i < n) out[i] = basew + s - v;
  if (t == 1023) partials[blockIdx.x] = wsum[15];
}

__global__ void partial_scan_kernel(int* __restrict__ partials, int nb) {
  const int lane = threadIdx.x & 63;
  int carry = 0;
  for (int base = 0; base < nb; base += 64) {
    const int i = base + lane;
    int v = (i < nb) ? partials[i] : 0;
    int s = v;
#pragma unroll
    for (int off = 1; off < 64; off <<= 1) {
      int u = __shfl_up(s, off, 64);
      if (lane >= off) s += u;
    }
    if (i < nb) partials[i] = carry + s - v;
    carry += __shfl(s, 63, 64);
  }
}

__global__ void add_offsets_kernel(int* __restrict__ soffs, const int* __restrict__ partials,
                                   int* __restrict__ cursor, int n) {
  const int i = blockIdx.x * 1024 + threadIdx.x;   // blockDim must be 1024
  if (i < n) {
    const int v = soffs[i] + partials[blockIdx.x];
    soffs[i] = v;
    cursor[i] = v;
  }
  if (i == 0) soffs[n] = NEDGE;
}

__global__ void seg_scatter_kernel(const int* __restrict__ src, const int* __restrict__ dst,
                                   const int* __restrict__ et, int* __restrict__ cursor,
                                   int* __restrict__ es, int e_cnt) {
  int e = blockIdx.x * 256 + threadIdx.x;
  if (e < e_cnt) {
    const int seg = dst[e] * NREL + et[e];
    const int p = atomicAdd(&cursor[seg], 1);
    es[p] = src[e];
  }
}

// ---------------------------------------------------------------- fp32 -> bf16
__global__ void cvt_bf16_kernel(const float4* __restrict__ in, ushort4* __restrict__ out, int n4) {
  int i = blockIdx.x * 256 + threadIdx.x;
  if (i < n4) {
    float4 f = in[i];
    ushort4 r;
    r.x = __builtin_bit_cast(unsigned short, __float2bfloat16(f.x));
    r.y = __builtin_bit_cast(unsigned short, __float2bfloat16(f.y));
    r.z = __builtin_bit_cast(unsigned short, __float2bfloat16(f.z));
    r.w = __builtin_bit_cast(unsigned short, __float2bfloat16(f.w));
    out[i] = r;
  }
}

// ------------------------------------------------- weight transpose (f32 src [rows][DIM] -> bf16 dst [DIM][GK])
__global__ void transpose_w_kernel(const float* __restrict__ src, __hip_bfloat16* __restrict__ dst,
                                   int rows, int col_off) {
  __shared__ float tile[32][33];
  const int c0 = blockIdx.x * 32;
  const int r0 = blockIdx.y * 32;
  const int tx = threadIdx.x, ty = threadIdx.y;  // 32x8
  for (int i = ty; i < 32; i += 8) {
    int r = r0 + i, c = c0 + tx;
    tile[i][tx] = (r < rows) ? src[(size_t)r * DIM + c] : 0.f;
  }
  __syncthreads();
  for (int i = ty; i < 32; i += 8) {
    int c = c0 + i, r = r0 + tx;
    if (r < rows)
      dst[(size_t)c * GK + col_off + r] = __float2bfloat16(tile[tx][i]);
  }
}

// ---------------------------------------------------------------- aggregation
// Edges pre-sorted by (dst, rel); soffs[n*8+r] gives contiguous segments.
// One wave owns a full 768-feature row (lane: 12 bf16 via 3x dwordx2 at
// boff + {0,512,1024}). Edge loop unrolled x4 -> 12 gathers in flight.
__global__ __launch_bounds__(256) void aggregate_kernel(
    const __hip_bfloat16* __restrict__ feat,  // [N_NODES][DIM] bf16
    const int* __restrict__ soffs, const int* __restrict__ es,
    __hip_bfloat16* __restrict__ Abuf,        // [caprows][GKA], chunk-local rows
    int node_base, int rows) {
  const int t = threadIdx.x;
  const int lane = t & 63;
  const int wave = t >> 6;
  const int boff = lane * 8;

  int nloc = (blockIdx.x * 4 + wave) * NPW;
  for (int it = 0; it < NPW; ++it, ++nloc) {
    if (nloc >= rows) return;
    const int n = node_base + nloc;
    char* Ab = (char*)(Abuf + (size_t)nloc * GKA);
#pragma unroll 1
    for (int r = 0; r < NREL; ++r) {
      const int beg = soffs[n * NREL + r], end = soffs[n * NREL + r + 1];
      float acc[12];
#pragma unroll
      for (int i = 0; i < 12; ++i) acc[i] = 0.f;
      int e = beg;
      for (; e + 4 <= end; e += 4) {
        uint2 v[4][3];
#pragma unroll
        for (int j = 0; j < 4; ++j) {
          const char* pp = (const char*)(feat + (size_t)es[e + j] * DIM) + boff;
          v[j][0] = *(const uint2*)(pp);
          v[j][1] = *(const uint2*)(pp + 512);
          v[j][2] = *(const uint2*)(pp + 1024);
        }
#pragma unroll
        for (int j = 0; j < 4; ++j) {
#pragma unroll
          for (int q = 0; q < 3; ++q) {
            acc[4 * q + 0] += bf_lo(v[j][q].x);
            acc[4 * q + 1] += bf_hi(v[j][q].x);
            acc[4 * q + 2] += bf_lo(v[j][q].y);
            acc[4 * q + 3] += bf_hi(v[j][q].y);
          }
        }
      }
      for (; e < end; ++e) {
        const char* pp = (const char*)(feat + (size_t)es[e] * DIM) + boff;
        uint2 a0 = *(const uint2*)(pp);
        uint2 a1 = *(const uint2*)(pp + 512);
        uint2 a2 = *(const uint2*)(pp + 1024);
        acc[0] += bf_lo(a0.x); acc[1] += bf_hi(a0.x); acc[2]  += bf_lo(a0.y); acc[3]  += bf_hi(a0.y);
        acc[4] += bf_lo(a1.x); acc[5] += bf_hi(a1.x); acc[6]  += bf_lo(a1.y); acc[7]  += bf_hi(a1.y);
        acc[8] += bf_lo(a2.x); acc[9] += bf_hi(a2.x); acc[10] += bf_lo(a2.y); acc[11] += bf_hi(a2.y);
      }
      const float inv = 1.f / fmaxf((float)(end - beg), 1.f);
      char* dst = Ab + r * (DIM * 2);
      uint2 o;
      o.x = pack_bf16x2(acc[0] * inv, acc[1] * inv);
      o.y = pack_bf16x2(acc[2] * inv, acc[3] * inv);
      *(uint2*)(dst + boff) = o;
      o.x = pack_bf16x2(acc[4] * inv, acc[5] * inv);
      o.y = pack_bf16x2(acc[6] * inv, acc[7] * inv);
      *(uint2*)(dst + boff + 512) = o;
      o.x = pack_bf16x2(acc[8] * inv, acc[9] * inv);
      o.y = pack_bf16x2(acc[10] * inv, acc[11] * inv);
      *(uint2*)(dst + boff + 1024) = o;
    }
  }
}

// ---------------------------------------------------------------- GEMM
// C[m,o] = sum_k Acat[m,k] * WT[o,k] (+bias).  Acat = [Amean (6144) | feat (768)].
// 128x256 tile, 512 threads (8 waves, 64x64 each), BK=64, combined 384-row LDS
// (A rows 0..127, B rows 128..383), global_load_lds width 16, XOR-swizzled,
// 16x16x32 bf16 MFMA. 3 column tiles per panel (was 6) -> A re-read halved;
// whole grid (471 blocks) is co-resident -> L3 serves panel re-reads.
__global__ __launch_bounds__(512, 4) void gemm_kernel(
    const __hip_bfloat16* __restrict__ A,     // [caprows][GKA] chunk-local
    const __hip_bfloat16* __restrict__ feat,  // [N_NODES][DIM] root operand
    const __hip_bfloat16* __restrict__ BT,    // [DIM][GK]
    const float* __restrict__ bias,           // [DIM]
    __hip_bfloat16* __restrict__ outb,        // mode 0: relu -> bf16 (global rows)
    float* __restrict__ outf,                 // mode 1: plain -> f32 (global rows)
    int mvalid, int node_base, int mode) {
  __shared__ __hip_bfloat16 Sm[384 * 64];     // 48 KB: A[0..127], B[128..383]
  const int t = threadIdx.x;
  const int lane = t & 63;
  const int wave = t >> 6;
  const int m0 = blockIdx.y * 128;
  const int n0 = blockIdx.x * 256;

  // staging: wave w covers combined rows w*48 .. w*48+47 in 6 insts of 8 rows.
  const int srow = lane >> 3;
  const int sg = (lane & 7) ^ srow;           // XOR-swizzled global granule
  const int crow0 = wave * 48;
  const __hip_bfloat16* gsrc[6];
#pragma unroll
  for (int ib = 0; ib < 6; ++ib) {
    const int rb = crow0 + ib * 8;            // multiple of 8
    if (rb < 128) gsrc[ib] = A + (size_t)(m0 + rb + srow) * GKA + sg * 8;
    else          gsrc[ib] = BT + (size_t)(n0 + rb - 128 + srow) * GK + sg * 8;
  }

  f32x4 acc[4][4] = {};
  const int wm = (wave >> 2) * 64;
  const int wn = (wave & 3) * 64;
  const int ml = lane & 15;
  const int quad = lane >> 4;
  const int sw = ml & 7;

  for (int kt = 0; kt < GK / 64; ++kt) {
    __syncthreads();
    if (kt == GKA / 64) {                      // switch A operand to root features
#pragma unroll
      for (int ib = 0; ib < 6; ++ib) {
        const int rb = crow0 + ib * 8;
        if (rb < 128)
          gsrc[ib] = feat + (size_t)(node_base + m0 + rb + srow) * DIM + sg * 8;
      }
    }
#pragma unroll
    for (int ib = 0; ib < 6; ++ib) {
      async_load16(gsrc[ib], &Sm[(crow0 + ib * 8) * 64]);
      gsrc[ib] += 64;
    }
    __syncthreads();
#pragma unroll
    for (int ks = 0; ks < 2; ++ks) {
      const int go = (((ks * 4 + quad) ^ sw) * 8);
      short8 a[4], b[4];
#pragma unroll
      for (int i = 0; i < 4; ++i) a[i] = *(const short8*)&Sm[(wm + i * 16 + ml) * 64 + go];
#pragma unroll
      for (int j = 0; j < 4; ++j) b[j] = *(const short8*)&Sm[(128 + wn + j * 16 + ml) * 64 + go];
#pragma unroll
      for (int i = 0; i < 4; ++i)
#pragma unroll
        for (int j = 0; j < 4; ++j)
          acc[i][j] = __builtin_amdgcn_mfma_f32_16x16x32_bf16(a[i], b[j], acc[i][j], 0, 0, 0);
    }
  }

  float bcol[4];
#pragma unroll
  for (int nt = 0; nt < 4; ++nt) bcol[nt] = bias[n0 + wn + nt * 16 + ml];
#pragma unroll
  for (int mt = 0; mt < 4; ++mt) {
#pragma unroll
    for (int rr = 0; rr < 4; ++rr) {
      int row = m0 + wm + mt * 16 + quad * 4 + rr;
      if (row < mvalid) {
        size_t orow = (size_t)(node_base + row) * DIM;
#pragma unroll
        for (int nt = 0; nt < 4; ++nt) {
          int col = n0 + wn + nt * 16 + ml;
          float v = acc[mt][nt][rr] + bcol[nt];
          if (mode == 0) outb[orow + col] = __float2bfloat16(fmaxf(v, 0.f));
          else           outf[orow + col] = v;
        }
      }
    }
  }
}

// ---------------------------------------------------------------- launch
extern "C" void kernel_launch(void* const* d_in, const int* in_sizes, int n_in,
                              void* d_out, int out_size, void* d_ws, size_t ws_size,
                              hipStream_t stream) {
  const float* x     = (const float*)d_in[0];
  const int*   eidx  = (const int*)d_in[1];     // [2][E]
  const int*   etype = (const int*)d_in[2];
  const float* W1    = (const float*)d_in[3];
  const float* root1 = (const float*)d_in[4];
  const float* b1    = (const float*)d_in[5];
  const float* W2    = (const float*)d_in[6];
  const float* root2 = (const float*)d_in[7];
  const float* b2    = (const float*)d_in[8];
  float* out = (float*)d_out;
  const int* esrc_in = eidx;
  const int* edst_in = eidx + NEDGE;

  char* p = (char*)d_ws;
  auto alloc = [&](size_t bytes) -> char* {
    char* r = p;
    p += (bytes + 255) & ~(size_t)255;
    return r;
  };
  __hip_bfloat16* xb  = (__hip_bfloat16*)alloc((size_t)N_NODES * DIM * 2);
  __hip_bfloat16* hb  = (__hip_bfloat16*)alloc((size_t)N_NODES * DIM * 2);
  __hip_bfloat16* w1t = (__hip_bfloat16*)alloc((size_t)DIM * GK * 2);
  __hip_bfloat16* w2t = (__hip_bfloat16*)alloc((size_t)DIM * GK * 2);
  int* segcnt   = (int*)alloc((size_t)NSEG * 4);
  int* soffs    = (int*)alloc((size_t)(NSEG + 1) * 4);
  int* cursor   = (int*)alloc((size_t)NSEG * 4);
  int* partials = (int*)alloc(256 * 4);
  int* es       = (int*)alloc((size_t)NEDGE * 4);
  size_t used = (size_t)(p - (char*)d_ws);
  size_t remain = (ws_size > used) ? (ws_size - used) : 0;
  long long caprows_ll = (long long)(remain / ((size_t)GKA * 2));
  int caprows = (int)((caprows_ll / 128) * 128);
  if (caprows > 20096) caprows = 20096;   // 157*128
  if (caprows < 128) caprows = 128;
  __hip_bfloat16* Abuf = (__hip_bfloat16*)p;

  // --- segment CSR build (edges sorted by (dst, rel)) ---
  const int NB = (NSEG + 1023) / 1024;    // 157
  hipMemsetAsync(segcnt, 0, (size_t)NSEG * 4, stream);
  seg_count_kernel<<<(NEDGE + 255) / 256, 256, 0, stream>>>(edst_in, etype, segcnt, NEDGE);
  block_scan_kernel<<<NB, 1024, 0, stream>>>(segcnt, soffs, partials, NSEG);
  partial_scan_kernel<<<1, 64, 0, stream>>>(partials, NB);
  add_offsets_kernel<<<NB, 1024, 0, stream>>>(soffs, partials, cursor, NSEG);
  seg_scatter_kernel<<<(NEDGE + 255) / 256, 256, 0, stream>>>(esrc_in, edst_in, etype, cursor, es, NEDGE);

  // --- convert x, build transposed bf16 weights ---
  cvt_bf16_kernel<<<((N_NODES * DIM / 4) + 255) / 256, 256, 0, stream>>>(
      (const float4*)x, (ushort4*)xb, N_NODES * DIM / 4);
  dim3 tb(32, 8);
  transpose_w_kernel<<<dim3(DIM / 32, (NREL * DIM) / 32), tb, 0, stream>>>(W1, w1t, NREL * DIM, 0);
  transpose_w_kernel<<<dim3(DIM / 32, DIM / 32), tb, 0, stream>>>(root1, w1t, DIM, NREL * DIM);
  transpose_w_kernel<<<dim3(DIM / 32, (NREL * DIM) / 32), tb, 0, stream>>>(W2, w2t, NREL * DIM, 0);
  transpose_w_kernel<<<dim3(DIM / 32, DIM / 32), tb, 0, stream>>>(root2, w2t, DIM, NREL * DIM);

  // --- layer 1: h = relu([mean_r(x) | x] @ W1cat + b1) -> bf16 ---
  for (int base = 0; base < N_NODES; base += caprows) {
    int rows = N_NODES - base; if (rows > caprows) rows = caprows;
    int agrid = (rows + 4 * NPW - 1) / (4 * NPW);
    aggregate_kernel<<<agrid, 256, 0, stream>>>(xb, soffs, es, Abuf, base, rows);
    dim3 grid(DIM / 256, (rows + 127) / 128);
    gemm_kernel<<<grid, 512, 0, stream>>>(Abuf, xb, w1t, b1, hb, nullptr, rows, base, 0);
  }
  // --- layer 2: out = [mean_r(h) | h] @ W2cat + b2 -> f32 ---
  for (int base = 0; base < N_NODES; base += caprows) {
    int rows = N_NODES - base; if (rows > caprows) rows = caprows;
    int agrid = (rows + 4 * NPW - 1) / (4 * NPW);
    aggregate_kernel<<<agrid, 256, 0, stream>>>(hb, soffs, es, Abuf, base, rows);
    dim3 grid(DIM / 256, (rows + 127) / 128);
    gemm_kernel<<<grid, 512, 0, stream>>>(Abuf, hb, w2t, b2, nullptr, out, rows, base, 1);
  }
}